// Round 8
// baseline (158.752 us; speedup 1.0000x reference)
//
#include <hip/hip_runtime.h>

// Problem sizes (compile-time)
constexpr int B_ = 16, T_ = 300, U_ = 30;
constexpr int V_ = 500;       // VOCAB
constexpr int BT_ = B_ * T_;  // 4800
constexpr int BU_ = B_ * U_;  // 480
constexpr int KD  = 512;      // K of all GEMMs
constexpr int NP  = 512;      // padded row stride

typedef __attribute__((ext_vector_type(8))) short short8v;  // 8 bf16
typedef __attribute__((ext_vector_type(4))) float f32x4;    // native 16B vector

__device__ __forceinline__ ushort f2bf(float f) {
    unsigned u = __builtin_bit_cast(unsigned, f);
    u += 0x7FFFu + ((u >> 16) & 1u);
    return (ushort)(u >> 16);
}

// direct global->LDS async copy, 16B per lane (wave-uniform LDS base)
#define GLOAD16(gsrc, ldst)                                                   \
    __builtin_amdgcn_global_load_lds(                                         \
        (const __attribute__((address_space(1))) unsigned int*)(const void*)(gsrc), \
        (__attribute__((address_space(3))) unsigned int*)(void*)(ldst), 16, 0, 0)

// ---------------------------------------------------------------------------
// prep2: role by blockIdx.x range
//  [0,128)   dec f32 -> decB bf16, rows 480..511 zeroed (512x512)
//  [128,192) W_enc^T -> WeT bf16
//  [192,256) W_dec^T -> WdT bf16
//  [256,384) W_out -> WoB bf16 (rows 500..511 zero) + be/bd bias dots
// ---------------------------------------------------------------------------
__global__ __launch_bounds__(256) void prep2(
    const float* __restrict__ dec,
    const float* __restrict__ W_enc, const float* __restrict__ W_dec,
    const float* __restrict__ W_out, const float* __restrict__ b_enc,
    const float* __restrict__ b_dec, const float* __restrict__ b_out,
    ushort* __restrict__ decB,
    ushort* __restrict__ WeT, ushort* __restrict__ WdT,
    ushort* __restrict__ WoB, float* __restrict__ be, float* __restrict__ bd)
{
    __shared__ ushort ts[64][65];
    const int bid = blockIdx.x;
    const int tid = threadIdx.x;

    if (bid < 128) {                        // dec convert + pad
        const size_t idx = (size_t)bid * 2048 + tid * 8;
        const int row = (int)(idx >> 9);
        short8v o = {};
        if (row < BU_) {
            float4 f0 = *reinterpret_cast<const float4*>(dec + idx);
            float4 f1 = *reinterpret_cast<const float4*>(dec + idx + 4);
            o[0]=(short)f2bf(f0.x); o[1]=(short)f2bf(f0.y);
            o[2]=(short)f2bf(f0.z); o[3]=(short)f2bf(f0.w);
            o[4]=(short)f2bf(f1.x); o[5]=(short)f2bf(f1.y);
            o[6]=(short)f2bf(f1.z); o[7]=(short)f2bf(f1.w);
        }
        *reinterpret_cast<short8v*>(decB + idx) = o;
    } else if (bid < 256) {                 // transpose W_enc / W_dec (64x64 tiles)
        const bool isE = bid < 192;
        const int t = bid - (isE ? 128 : 192);     // 0..63
        const float*  W = isE ? W_enc : W_dec;
        ushort*      WT = isE ? WeT : WdT;
        const int r0 = (t >> 3) * 64, c0 = (t & 7) * 64;
        #pragma unroll
        for (int it = 0; it < 4; ++it) {
            const int idx = tid + it * 256;
            const int r = idx >> 4, c4 = (idx & 15) * 4;
            float4 f = *reinterpret_cast<const float4*>(&W[(size_t)(r0 + r) * 512 + c0 + c4]);
            ts[r][c4 + 0] = f2bf(f.x); ts[r][c4 + 1] = f2bf(f.y);
            ts[r][c4 + 2] = f2bf(f.z); ts[r][c4 + 3] = f2bf(f.w);
        }
        __syncthreads();
        #pragma unroll
        for (int it = 0; it < 4; ++it) {
            const int idx = tid + it * 256;
            const int c = idx >> 4, r4 = (idx & 15) * 4;
            ushort4 o;
            o.x = ts[r4 + 0][c]; o.y = ts[r4 + 1][c];
            o.z = ts[r4 + 2][c]; o.w = ts[r4 + 3][c];
            *reinterpret_cast<ushort4*>(&WT[(size_t)(c0 + c) * 512 + r0 + r4]) = o;
        }
    } else {                                // W_out rows + folded biases
        const int v    = (bid - 256) * 4 + (tid >> 6);  // 0..511
        const int lane = tid & 63;
        float4 f0 = make_float4(0, 0, 0, 0), f1 = f0;
        if (v < V_) {
            f0 = *reinterpret_cast<const float4*>(&W_out[(size_t)v * 512 + lane * 8]);
            f1 = *reinterpret_cast<const float4*>(&W_out[(size_t)v * 512 + lane * 8 + 4]);
        }
        short8v o; o[0]=(short)f2bf(f0.x); o[1]=(short)f2bf(f0.y);
        o[2]=(short)f2bf(f0.z); o[3]=(short)f2bf(f0.w);
        o[4]=(short)f2bf(f1.x); o[5]=(short)f2bf(f1.y);
        o[6]=(short)f2bf(f1.z); o[7]=(short)f2bf(f1.w);
        *reinterpret_cast<short8v*>(WoB + (size_t)v * 512 + lane * 8) = o;

        float4 e0 = *reinterpret_cast<const float4*>(b_enc + lane * 8);
        float4 e1 = *reinterpret_cast<const float4*>(b_enc + lane * 8 + 4);
        float4 d0 = *reinterpret_cast<const float4*>(b_dec + lane * 8);
        float4 d1 = *reinterpret_cast<const float4*>(b_dec + lane * 8 + 4);
        float sE = f0.x*e0.x + f0.y*e0.y + f0.z*e0.z + f0.w*e0.w
                 + f1.x*e1.x + f1.y*e1.y + f1.z*e1.z + f1.w*e1.w;
        float sD = f0.x*d0.x + f0.y*d0.y + f0.z*d0.z + f0.w*d0.w
                 + f1.x*d1.x + f1.y*d1.y + f1.z*d1.z + f1.w*d1.w;
        #pragma unroll
        for (int off = 32; off > 0; off >>= 1) {
            sE += __shfl_down(sE, off);
            sD += __shfl_down(sD, off);
        }
        if (lane == 0) {
            be[v] = (v < V_) ? sE : 0.0f;
            bd[v] = (v < V_) ? (sD + b_out[v]) : 0.0f;
        }
    }
}

// ---------------------------------------------------------------------------
// bf16 NT GEMM body — round-3 exact (single-buffer BK=32, known-good).
// ---------------------------------------------------------------------------
template <bool OUT_BF16>
__device__ __forceinline__ void gemm_body(
    const ushort* __restrict__ A, const ushort* __restrict__ Bm,
    const float* __restrict__ bias, void* __restrict__ C,
    int m0, int n0)
{
    __shared__ ushort a_s[64 * 32];
    __shared__ ushort b_s[64 * 32];

    const int tid  = threadIdx.x;
    const int lane = tid & 63;
    const int wave = tid >> 6;
    const int wm   = wave >> 1, wn = wave & 1;

    ushort* a_dst = a_s + wave * 512;
    ushort* b_dst = b_s + wave * 512;
    const int srow = (wave << 4) + (lane >> 2);
    const int skc  = (lane & 3) * 8;

    const int r16 = lane & 15;
    const int kc  = lane >> 4;

    f32x4 acc[2][2] = {};

    for (int k0 = 0; k0 < KD; k0 += 32) {
        GLOAD16(A  + (size_t)(m0 + srow) * KD + k0 + skc, a_dst);
        GLOAD16(Bm + (size_t)(n0 + srow) * KD + k0 + skc, b_dst);
        __syncthreads();

        const short8v af0 = *reinterpret_cast<const short8v*>(&a_s[(wm*32 +      r16) * 32 + kc*8]);
        const short8v af1 = *reinterpret_cast<const short8v*>(&a_s[(wm*32 + 16 + r16) * 32 + kc*8]);
        const short8v bf0 = *reinterpret_cast<const short8v*>(&b_s[(wn*32 +      r16) * 32 + kc*8]);
        const short8v bf1 = *reinterpret_cast<const short8v*>(&b_s[(wn*32 + 16 + r16) * 32 + kc*8]);

        acc[0][0] = __builtin_amdgcn_mfma_f32_16x16x32_bf16(af0, bf0, acc[0][0], 0, 0, 0);
        acc[0][1] = __builtin_amdgcn_mfma_f32_16x16x32_bf16(af0, bf1, acc[0][1], 0, 0, 0);
        acc[1][0] = __builtin_amdgcn_mfma_f32_16x16x32_bf16(af1, bf0, acc[1][0], 0, 0, 0);
        acc[1][1] = __builtin_amdgcn_mfma_f32_16x16x32_bf16(af1, bf1, acc[1][1], 0, 0, 0);
        __syncthreads();
    }

    const int rb = (lane >> 4) * 4;
    #pragma unroll
    for (int m = 0; m < 2; ++m) {
        const int grow0 = m0 + wm * 32 + m * 16 + rb;
        #pragma unroll
        for (int n = 0; n < 2; ++n) {
            const int gcol = n0 + wn * 32 + n * 16 + r16;
            const float bv = bias ? bias[gcol] : 0.0f;
            #pragma unroll
            for (int r = 0; r < 4; ++r) {
                const float v = acc[m][n][r] + bv;
                if constexpr (OUT_BF16)
                    ((ushort*)C)[(size_t)(grow0 + r) * NP + gcol] = f2bf(v);
                else
                    ((float*)C)[(size_t)(grow0 + r) * NP + gcol] = v;
            }
        }
    }
}

// Wc_enc = WoB @ WeT^T (z=0), Wc_dec = WoB @ WdT^T (z=1); 512x512 bf16 out
__global__ __launch_bounds__(256) void wc_gemm(
    const ushort* __restrict__ WoB, const ushort* __restrict__ WeT,
    const ushort* __restrict__ WdT, ushort* __restrict__ WcE,
    ushort* __restrict__ WcD)
{
    const bool z = blockIdx.z != 0;
    gemm_body<true>(WoB, z ? WdT : WeT, nullptr, z ? WcD : WcE,
                    blockIdx.y * 64, blockIdx.x * 64);
}

// DV = decB @ WcD^T + bd   (512x512 f32; rows >= 480 garbage-but-unread)
__global__ __launch_bounds__(256) void dv_gemm(
    const ushort* __restrict__ decB, const ushort* __restrict__ WcD,
    const float* __restrict__ bd, float* __restrict__ DV)
{
    gemm_body<false>(decB, WcD, bd, DV, blockIdx.y * 64, blockIdx.x * 64);
}

// ---------------------------------------------------------------------------
// Fused EV GEMM + broadcast-add + contiguous output stream.
// Block = 6 bt-rows x FULL V; grid = 16 b x 50 tiles = 800 blocks (3.1/CU).
// Per block: A (6x512) read per-lane from enc (f32->bf16 in-reg); B-fragments
// direct from L2-resident WcE; EV via 12KB LDS; DV slice in 8 regs/thread;
// output = one contiguous 360 KB nontemporal stream.
// ---------------------------------------------------------------------------
constexpr int RT = 6;                 // bt-rows per tile (300 = 6*50)

__global__ __launch_bounds__(512) void fused_ev_stream(
    const float* __restrict__ enc, const ushort* __restrict__ WcE,
    const float* __restrict__ be, const float* __restrict__ DV,
    float* __restrict__ out)
{
    __shared__ float evs[RT * 512];   // 12 KB

    const int tid  = threadIdx.x;
    const int lane = tid & 63;
    const int wave = tid >> 6;        // 0..7 -> 64-col strip
    const int b    = blockIdx.x / 50;
    const int tile = blockIdx.x - b * 50;
    const int bt0  = b * T_ + tile * RT;

    const int r16 = lane & 15;
    const int kc8 = (lane >> 4) * 8;
    const int cb  = wave * 64;
    const int arow = (r16 < RT) ? r16 : (RT - 1);
    const float* aptr = enc + (size_t)(bt0 + arow) * KD + kc8;

    f32x4 acc[4] = {};

    #pragma unroll 4
    for (int k0 = 0; k0 < KD; k0 += 32) {
        const float4 f0 = *reinterpret_cast<const float4*>(aptr + k0);
        const float4 f1 = *reinterpret_cast<const float4*>(aptr + k0 + 4);
        short8v a;
        a[0]=(short)f2bf(f0.x); a[1]=(short)f2bf(f0.y);
        a[2]=(short)f2bf(f0.z); a[3]=(short)f2bf(f0.w);
        a[4]=(short)f2bf(f1.x); a[5]=(short)f2bf(f1.y);
        a[6]=(short)f2bf(f1.z); a[7]=(short)f2bf(f1.w);
        #pragma unroll
        for (int n = 0; n < 4; ++n) {
            const short8v bf = *reinterpret_cast<const short8v*>(
                WcE + (size_t)(cb + n * 16 + r16) * KD + k0 + kc8);
            acc[n] = __builtin_amdgcn_mfma_f32_16x16x32_bf16(a, bf, acc[n], 0, 0, 0);
        }
    }

    // ---- evs = acc + be (valid rows/cols only) ----
    const int rb = (lane >> 4) * 4;   // row group base: 0,4,8,12
    #pragma unroll
    for (int n = 0; n < 4; ++n) {
        const int col = cb + n * 16 + r16;
        if (col < V_) {
            const float bv = be[col];
            #pragma unroll
            for (int r = 0; r < 4; ++r) {
                const int row = rb + r;
                if (row < RT)
                    evs[row * 512 + col] = acc[n][r] + bv;
            }
        }
    }
    __syncthreads();

    // ---- DV slice -> regs (u = ug + 4j), then contiguous stream ----
    const int v4 = tid & 127;         // 0..127, <125 active
    const int ug = tid >> 7;          // 0..3
    const bool vact = v4 < 125;

    f32x4 dreg[8] = {};
    if (vact) {
        #pragma unroll
        for (int j = 0; j < 8; ++j) {
            const int u = ug + 4 * j;
            if (u < U_)
                dreg[j] = *reinterpret_cast<const f32x4*>(
                    DV + ((size_t)b * U_ + u) * NP + v4 * 4);
        }
    }

    if (vact) {
        #pragma unroll
        for (int r = 0; r < RT; ++r) {
            const f32x4 e = *reinterpret_cast<const f32x4*>(&evs[r * 512 + v4 * 4]);
            float* orow = out + ((size_t)(bt0 + r) * U_) * V_ + v4 * 4;
            #pragma unroll
            for (int j = 0; j < 8; ++j) {
                const int u = ug + 4 * j;
                if (u < U_)
                    __builtin_nontemporal_store(
                        e + dreg[j], reinterpret_cast<f32x4*>(orow + (size_t)u * V_));
            }
        }
    }
}

extern "C" void kernel_launch(void* const* d_in, const int* in_sizes, int n_in,
                              void* d_out, int out_size, void* d_ws, size_t ws_size,
                              hipStream_t stream) {
    const float* enc   = (const float*)d_in[0];
    const float* dec   = (const float*)d_in[1];
    const float* W_enc = (const float*)d_in[2];
    const float* b_enc = (const float*)d_in[3];
    const float* W_dec = (const float*)d_in[4];
    const float* b_dec = (const float*)d_in[5];
    const float* W_out = (const float*)d_in[6];
    const float* b_out = (const float*)d_in[7];
    float* out = (float*)d_out;

    // Workspace (~4.2 MB)
    char* p = (char*)d_ws;
    ushort* decB = (ushort*)p;            p += (size_t)512 * 512 * 2;
    ushort* WeT  = (ushort*)p;            p += (size_t)512 * 512 * 2;
    ushort* WdT  = (ushort*)p;            p += (size_t)512 * 512 * 2;
    ushort* WoB  = (ushort*)p;            p += (size_t)512 * 512 * 2;
    ushort* WcE  = (ushort*)p;            p += (size_t)512 * 512 * 2;
    ushort* WcD  = (ushort*)p;            p += (size_t)512 * 512 * 2;
    float*  be   = (float*)p;             p += 512 * 4;
    float*  bd   = (float*)p;             p += 512 * 4;
    float*  DV   = (float*)p;                                  // 512x512 f32

    prep2<<<dim3(384), dim3(256), 0, stream>>>(
        dec, W_enc, W_dec, W_out, b_enc, b_dec, b_out,
        decB, WeT, WdT, WoB, be, bd);

    wc_gemm<<<dim3(8, 8, 2), dim3(256), 0, stream>>>(WoB, WeT, WdT, WcE, WcD);

    dv_gemm<<<dim3(8, 8), dim3(256), 0, stream>>>(decB, WcD, bd, DV);

    fused_ev_stream<<<dim3(800), dim3(512), 0, stream>>>(
        enc, WcE, be, DV, out);
}

// Round 9
// 111.216 us; speedup vs baseline: 1.4274x; 1.4274x over previous
//
#include <hip/hip_runtime.h>

// Problem sizes (compile-time)
constexpr int B_ = 16, T_ = 300, U_ = 30;
constexpr int V_ = 500;       // VOCAB
constexpr int BT_ = B_ * T_;  // 4800
constexpr int BU_ = B_ * U_;  // 480
constexpr int KD  = 512;      // K of all GEMMs
constexpr int NP  = 512;      // padded row stride

typedef __attribute__((ext_vector_type(8))) short short8v;  // 8 bf16
typedef __attribute__((ext_vector_type(4))) float f32x4;    // native 16B vector

__device__ __forceinline__ ushort f2bf(float f) {
    unsigned u = __builtin_bit_cast(unsigned, f);
    u += 0x7FFFu + ((u >> 16) & 1u);
    return (ushort)(u >> 16);
}

// direct global->LDS async copy, 16B per lane (wave-uniform LDS base)
#define GLOAD16(gsrc, ldst)                                                   \
    __builtin_amdgcn_global_load_lds(                                         \
        (const __attribute__((address_space(1))) unsigned int*)(const void*)(gsrc), \
        (__attribute__((address_space(3))) unsigned int*)(void*)(ldst), 16, 0, 0)

// ---------------------------------------------------------------------------
// prep2: role by blockIdx.x range
//  [0,128)   dec f32 -> decB bf16, rows 480..511 zeroed (512x512)
//  [128,192) W_enc^T -> WeT bf16
//  [192,256) W_dec^T -> WdT bf16
//  [256,384) W_out -> WoB bf16 (rows 500..511 zero) + be/bd bias dots
// ---------------------------------------------------------------------------
__global__ __launch_bounds__(256) void prep2(
    const float* __restrict__ dec,
    const float* __restrict__ W_enc, const float* __restrict__ W_dec,
    const float* __restrict__ W_out, const float* __restrict__ b_enc,
    const float* __restrict__ b_dec, const float* __restrict__ b_out,
    ushort* __restrict__ decB,
    ushort* __restrict__ WeT, ushort* __restrict__ WdT,
    ushort* __restrict__ WoB, float* __restrict__ be, float* __restrict__ bd)
{
    __shared__ ushort ts[64][65];
    const int bid = blockIdx.x;
    const int tid = threadIdx.x;

    if (bid < 128) {                        // dec convert + pad
        const size_t idx = (size_t)bid * 2048 + tid * 8;
        const int row = (int)(idx >> 9);
        short8v o = {};
        if (row < BU_) {
            float4 f0 = *reinterpret_cast<const float4*>(dec + idx);
            float4 f1 = *reinterpret_cast<const float4*>(dec + idx + 4);
            o[0]=(short)f2bf(f0.x); o[1]=(short)f2bf(f0.y);
            o[2]=(short)f2bf(f0.z); o[3]=(short)f2bf(f0.w);
            o[4]=(short)f2bf(f1.x); o[5]=(short)f2bf(f1.y);
            o[6]=(short)f2bf(f1.z); o[7]=(short)f2bf(f1.w);
        }
        *reinterpret_cast<short8v*>(decB + idx) = o;
    } else if (bid < 256) {                 // transpose W_enc / W_dec (64x64 tiles)
        const bool isE = bid < 192;
        const int t = bid - (isE ? 128 : 192);     // 0..63
        const float*  W = isE ? W_enc : W_dec;
        ushort*      WT = isE ? WeT : WdT;
        const int r0 = (t >> 3) * 64, c0 = (t & 7) * 64;
        #pragma unroll
        for (int it = 0; it < 4; ++it) {
            const int idx = tid + it * 256;
            const int r = idx >> 4, c4 = (idx & 15) * 4;
            float4 f = *reinterpret_cast<const float4*>(&W[(size_t)(r0 + r) * 512 + c0 + c4]);
            ts[r][c4 + 0] = f2bf(f.x); ts[r][c4 + 1] = f2bf(f.y);
            ts[r][c4 + 2] = f2bf(f.z); ts[r][c4 + 3] = f2bf(f.w);
        }
        __syncthreads();
        #pragma unroll
        for (int it = 0; it < 4; ++it) {
            const int idx = tid + it * 256;
            const int c = idx >> 4, r4 = (idx & 15) * 4;
            ushort4 o;
            o.x = ts[r4 + 0][c]; o.y = ts[r4 + 1][c];
            o.z = ts[r4 + 2][c]; o.w = ts[r4 + 3][c];
            *reinterpret_cast<ushort4*>(&WT[(size_t)(c0 + c) * 512 + r0 + r4]) = o;
        }
    } else {                                // W_out rows + folded biases
        const int v    = (bid - 256) * 4 + (tid >> 6);  // 0..511
        const int lane = tid & 63;
        float4 f0 = make_float4(0, 0, 0, 0), f1 = f0;
        if (v < V_) {
            f0 = *reinterpret_cast<const float4*>(&W_out[(size_t)v * 512 + lane * 8]);
            f1 = *reinterpret_cast<const float4*>(&W_out[(size_t)v * 512 + lane * 8 + 4]);
        }
        short8v o; o[0]=(short)f2bf(f0.x); o[1]=(short)f2bf(f0.y);
        o[2]=(short)f2bf(f0.z); o[3]=(short)f2bf(f0.w);
        o[4]=(short)f2bf(f1.x); o[5]=(short)f2bf(f1.y);
        o[6]=(short)f2bf(f1.z); o[7]=(short)f2bf(f1.w);
        *reinterpret_cast<short8v*>(WoB + (size_t)v * 512 + lane * 8) = o;

        float4 e0 = *reinterpret_cast<const float4*>(b_enc + lane * 8);
        float4 e1 = *reinterpret_cast<const float4*>(b_enc + lane * 8 + 4);
        float4 d0 = *reinterpret_cast<const float4*>(b_dec + lane * 8);
        float4 d1 = *reinterpret_cast<const float4*>(b_dec + lane * 8 + 4);
        float sE = f0.x*e0.x + f0.y*e0.y + f0.z*e0.z + f0.w*e0.w
                 + f1.x*e1.x + f1.y*e1.y + f1.z*e1.z + f1.w*e1.w;
        float sD = f0.x*d0.x + f0.y*d0.y + f0.z*d0.z + f0.w*d0.w
                 + f1.x*d1.x + f1.y*d1.y + f1.z*d1.z + f1.w*d1.w;
        #pragma unroll
        for (int off = 32; off > 0; off >>= 1) {
            sE += __shfl_down(sE, off);
            sD += __shfl_down(sD, off);
        }
        if (lane == 0) {
            be[v] = (v < V_) ? sE : 0.0f;
            bd[v] = (v < V_) ? (sD + b_out[v]) : 0.0f;
        }
    }
}

// ---------------------------------------------------------------------------
// bf16 NT GEMM body — round-3 exact (single-buffer BK=32, known-good).
// ---------------------------------------------------------------------------
template <bool OUT_BF16>
__device__ __forceinline__ void gemm_body(
    const ushort* __restrict__ A, const ushort* __restrict__ Bm,
    const float* __restrict__ bias, void* __restrict__ C,
    int m0, int n0)
{
    __shared__ ushort a_s[64 * 32];
    __shared__ ushort b_s[64 * 32];

    const int tid  = threadIdx.x;
    const int lane = tid & 63;
    const int wave = tid >> 6;
    const int wm   = wave >> 1, wn = wave & 1;

    ushort* a_dst = a_s + wave * 512;
    ushort* b_dst = b_s + wave * 512;
    const int srow = (wave << 4) + (lane >> 2);
    const int skc  = (lane & 3) * 8;

    const int r16 = lane & 15;
    const int kc  = lane >> 4;

    f32x4 acc[2][2] = {};

    for (int k0 = 0; k0 < KD; k0 += 32) {
        GLOAD16(A  + (size_t)(m0 + srow) * KD + k0 + skc, a_dst);
        GLOAD16(Bm + (size_t)(n0 + srow) * KD + k0 + skc, b_dst);
        __syncthreads();

        const short8v af0 = *reinterpret_cast<const short8v*>(&a_s[(wm*32 +      r16) * 32 + kc*8]);
        const short8v af1 = *reinterpret_cast<const short8v*>(&a_s[(wm*32 + 16 + r16) * 32 + kc*8]);
        const short8v bf0 = *reinterpret_cast<const short8v*>(&b_s[(wn*32 +      r16) * 32 + kc*8]);
        const short8v bf1 = *reinterpret_cast<const short8v*>(&b_s[(wn*32 + 16 + r16) * 32 + kc*8]);

        acc[0][0] = __builtin_amdgcn_mfma_f32_16x16x32_bf16(af0, bf0, acc[0][0], 0, 0, 0);
        acc[0][1] = __builtin_amdgcn_mfma_f32_16x16x32_bf16(af0, bf1, acc[0][1], 0, 0, 0);
        acc[1][0] = __builtin_amdgcn_mfma_f32_16x16x32_bf16(af1, bf0, acc[1][0], 0, 0, 0);
        acc[1][1] = __builtin_amdgcn_mfma_f32_16x16x32_bf16(af1, bf1, acc[1][1], 0, 0, 0);
        __syncthreads();
    }

    const int rb = (lane >> 4) * 4;
    #pragma unroll
    for (int m = 0; m < 2; ++m) {
        const int grow0 = m0 + wm * 32 + m * 16 + rb;
        #pragma unroll
        for (int n = 0; n < 2; ++n) {
            const int gcol = n0 + wn * 32 + n * 16 + r16;
            const float bv = bias ? bias[gcol] : 0.0f;
            #pragma unroll
            for (int r = 0; r < 4; ++r) {
                const float v = acc[m][n][r] + bv;
                if constexpr (OUT_BF16)
                    ((ushort*)C)[(size_t)(grow0 + r) * NP + gcol] = f2bf(v);
                else
                    ((float*)C)[(size_t)(grow0 + r) * NP + gcol] = v;
            }
        }
    }
}

// Wc_enc = WoB @ WeT^T (z=0), Wc_dec = WoB @ WdT^T (z=1); 512x512 bf16 out
__global__ __launch_bounds__(256) void wc_gemm(
    const ushort* __restrict__ WoB, const ushort* __restrict__ WeT,
    const ushort* __restrict__ WdT, ushort* __restrict__ WcE,
    ushort* __restrict__ WcD)
{
    const bool z = blockIdx.z != 0;
    gemm_body<true>(WoB, z ? WdT : WeT, nullptr, z ? WcD : WcE,
                    blockIdx.y * 64, blockIdx.x * 64);
}

// DV = decB @ WcD^T + bd   (512x512 f32; rows >= 480 garbage-but-unread)
__global__ __launch_bounds__(256) void dv_gemm(
    const ushort* __restrict__ decB, const ushort* __restrict__ WcD,
    const float* __restrict__ bd, float* __restrict__ DV)
{
    gemm_body<false>(decB, WcD, bd, DV, blockIdx.y * 64, blockIdx.x * 64);
}

// ---------------------------------------------------------------------------
// Fused EV GEMM + broadcast-add + contiguous output stream.
// Block = 12 bt-rows x FULL V; grid = 16 b x 25 tiles = 400 blocks, 256 thr.
//  - A (12x512 f32 -> bf16) staged ONCE in LDS [16][520] (rows 12..15 zero)
//  - 4 waves x 128-col strips; 8 indep B-loads + 8 MFMA per k-step (ILP)
//  - B-fragments direct from L2-resident WcE (512 KB)
//  - EV via LDS [16][516] f32; DV slice in 15 regs/thread
//  - output: one contiguous 720 KB nontemporal stream per block
// LDS = 16.6K + 33K = 49.6 KB -> up to 3 blocks/CU.
// ---------------------------------------------------------------------------
constexpr int RT = 12;                // bt-rows per tile (300 = 12*25)

__global__ __launch_bounds__(256) void fused_ev_stream(
    const float* __restrict__ enc, const ushort* __restrict__ WcE,
    const float* __restrict__ be, const float* __restrict__ DV,
    float* __restrict__ out)
{
    __shared__ ushort a_s[16 * 520];  // bf16 A tile, stride 520 (2-way banks)
    __shared__ float  evs[16 * 516];  // f32 EV tile, stride 516 (2-way banks)

    const int tid  = threadIdx.x;
    const int lane = tid & 63;
    const int wave = tid >> 6;        // 0..3 -> 128-col strip
    const int b    = blockIdx.x / 25;
    const int tile = blockIdx.x - b * 25;
    const int bt0  = b * T_ + tile * RT;

    // ---- stage A: 16 rows x 512 cols, f32 -> bf16, rows >= RT zeroed ----
    #pragma unroll
    for (int it = 0; it < 8; ++it) {
        const int flat = it * 1024 + tid * 4;      // f32 index in 16x512
        const int r = flat >> 9;
        const int c = flat & 511;
        float4 f = make_float4(0.f, 0.f, 0.f, 0.f);
        if (r < RT)
            f = *reinterpret_cast<const float4*>(enc + (size_t)(bt0 + r) * KD + c);
        ushort4 o;
        o.x = f2bf(f.x); o.y = f2bf(f.y); o.z = f2bf(f.z); o.w = f2bf(f.w);
        *reinterpret_cast<ushort4*>(&a_s[r * 520 + c]) = o;
    }
    __syncthreads();

    // ---- GEMM: 16 rows x 128 cols per wave, K=512, B from L2 ----
    const int r16 = lane & 15;
    const int kc8 = (lane >> 4) * 8;
    const int cb  = wave * 128;
    f32x4 acc[8] = {};

    #pragma unroll 2
    for (int k0 = 0; k0 < KD; k0 += 32) {
        const short8v a0 = *reinterpret_cast<const short8v*>(&a_s[r16 * 520 + k0 + kc8]);
        #pragma unroll
        for (int n = 0; n < 8; ++n) {
            const short8v bf = *reinterpret_cast<const short8v*>(
                WcE + (size_t)(cb + n * 16 + r16) * KD + k0 + kc8);
            acc[n] = __builtin_amdgcn_mfma_f32_16x16x32_bf16(a0, bf, acc[n], 0, 0, 0);
        }
    }

    // ---- evs = acc + be ----
    const int rb = (lane >> 4) * 4;
    #pragma unroll
    for (int n = 0; n < 8; ++n) {
        const int col = cb + n * 16 + r16;
        if (col < V_) {
            const float bv = be[col];
            #pragma unroll
            for (int r = 0; r < 4; ++r)
                evs[(rb + r) * 516 + col] = acc[n][r] + bv;
        }
    }
    __syncthreads();

    // ---- DV slice -> 15 regs (u = 2j + ug), then contiguous nt-stream ----
    const int v4 = tid & 127;         // 0..127, <125 active
    const int ug = tid >> 7;          // 0..1
    if (v4 < 125) {
        f32x4 dreg[15];
        #pragma unroll
        for (int j = 0; j < 15; ++j) {
            const int u = 2 * j + ug;
            dreg[j] = *reinterpret_cast<const f32x4*>(
                DV + ((size_t)b * U_ + u) * NP + v4 * 4);
        }
        #pragma unroll
        for (int r = 0; r < RT; ++r) {
            const f32x4 e = *reinterpret_cast<const f32x4*>(&evs[r * 516 + v4 * 4]);
            float* base = out + ((size_t)(bt0 + r) * U_ + ug) * V_ + v4 * 4;
            #pragma unroll
            for (int j = 0; j < 15; ++j)
                __builtin_nontemporal_store(
                    e + dreg[j], reinterpret_cast<f32x4*>(base + j * (2 * V_)));
        }
    }
}

extern "C" void kernel_launch(void* const* d_in, const int* in_sizes, int n_in,
                              void* d_out, int out_size, void* d_ws, size_t ws_size,
                              hipStream_t stream) {
    const float* enc   = (const float*)d_in[0];
    const float* dec   = (const float*)d_in[1];
    const float* W_enc = (const float*)d_in[2];
    const float* b_enc = (const float*)d_in[3];
    const float* W_dec = (const float*)d_in[4];
    const float* b_dec = (const float*)d_in[5];
    const float* W_out = (const float*)d_in[6];
    const float* b_out = (const float*)d_in[7];
    float* out = (float*)d_out;

    // Workspace (~4.2 MB)
    char* p = (char*)d_ws;
    ushort* decB = (ushort*)p;            p += (size_t)512 * 512 * 2;
    ushort* WeT  = (ushort*)p;            p += (size_t)512 * 512 * 2;
    ushort* WdT  = (ushort*)p;            p += (size_t)512 * 512 * 2;
    ushort* WoB  = (ushort*)p;            p += (size_t)512 * 512 * 2;
    ushort* WcE  = (ushort*)p;            p += (size_t)512 * 512 * 2;
    ushort* WcD  = (ushort*)p;            p += (size_t)512 * 512 * 2;
    float*  be   = (float*)p;             p += 512 * 4;
    float*  bd   = (float*)p;             p += 512 * 4;
    float*  DV   = (float*)p;                                  // 512x512 f32

    prep2<<<dim3(384), dim3(256), 0, stream>>>(
        dec, W_enc, W_dec, W_out, b_enc, b_dec, b_out,
        decB, WeT, WdT, WoB, be, bd);

    wc_gemm<<<dim3(8, 8, 2), dim3(256), 0, stream>>>(WoB, WeT, WdT, WcE, WcD);

    dv_gemm<<<dim3(8, 8), dim3(256), 0, stream>>>(decB, WcD, bd, DV);

    fused_ev_stream<<<dim3(400), dim3(256), 0, stream>>>(
        enc, WcE, be, DV, out);
}

// Round 10
// 89.217 us; speedup vs baseline: 1.7794x; 1.2466x over previous
//
#include <hip/hip_runtime.h>

// Problem sizes (compile-time)
constexpr int B_ = 16, T_ = 300, U_ = 30;
constexpr int V_ = 500;       // VOCAB
constexpr int BT_ = B_ * T_;  // 4800
constexpr int BU_ = B_ * U_;  // 480
constexpr int KD  = 512;      // K of all GEMMs
constexpr int NP  = 512;      // padded row stride

typedef __attribute__((ext_vector_type(8))) short short8v;  // 8 bf16
typedef __attribute__((ext_vector_type(4))) float f32x4;    // native 16B vector

__device__ __forceinline__ ushort f2bf(float f) {
    unsigned u = __builtin_bit_cast(unsigned, f);
    u += 0x7FFFu + ((u >> 16) & 1u);
    return (ushort)(u >> 16);
}

// direct global->LDS async copy, 16B per lane (wave-uniform LDS base)
#define GLOAD16(gsrc, ldst)                                                   \
    __builtin_amdgcn_global_load_lds(                                         \
        (const __attribute__((address_space(1))) unsigned int*)(const void*)(gsrc), \
        (__attribute__((address_space(3))) unsigned int*)(void*)(ldst), 16, 0, 0)

// ---------------------------------------------------------------------------
// prep2: role by blockIdx.x range
//  [0,128)   dec f32 -> decB bf16, rows 480..511 zeroed (512x512)
//  [128,192) W_enc^T -> WeT bf16
//  [192,256) W_dec^T -> WdT bf16
//  [256,384) W_out -> WoB bf16 (rows 500..511 zero) + be/bd bias dots
// ---------------------------------------------------------------------------
__global__ __launch_bounds__(256) void prep2(
    const float* __restrict__ dec,
    const float* __restrict__ W_enc, const float* __restrict__ W_dec,
    const float* __restrict__ W_out, const float* __restrict__ b_enc,
    const float* __restrict__ b_dec, const float* __restrict__ b_out,
    ushort* __restrict__ decB,
    ushort* __restrict__ WeT, ushort* __restrict__ WdT,
    ushort* __restrict__ WoB, float* __restrict__ be, float* __restrict__ bd)
{
    __shared__ ushort ts[64][65];
    const int bid = blockIdx.x;
    const int tid = threadIdx.x;

    if (bid < 128) {                        // dec convert + pad
        const size_t idx = (size_t)bid * 2048 + tid * 8;
        const int row = (int)(idx >> 9);
        short8v o = {};
        if (row < BU_) {
            float4 f0 = *reinterpret_cast<const float4*>(dec + idx);
            float4 f1 = *reinterpret_cast<const float4*>(dec + idx + 4);
            o[0]=(short)f2bf(f0.x); o[1]=(short)f2bf(f0.y);
            o[2]=(short)f2bf(f0.z); o[3]=(short)f2bf(f0.w);
            o[4]=(short)f2bf(f1.x); o[5]=(short)f2bf(f1.y);
            o[6]=(short)f2bf(f1.z); o[7]=(short)f2bf(f1.w);
        }
        *reinterpret_cast<short8v*>(decB + idx) = o;
    } else if (bid < 256) {                 // transpose W_enc / W_dec (64x64 tiles)
        const bool isE = bid < 192;
        const int t = bid - (isE ? 128 : 192);     // 0..63
        const float*  W = isE ? W_enc : W_dec;
        ushort*      WT = isE ? WeT : WdT;
        const int r0 = (t >> 3) * 64, c0 = (t & 7) * 64;
        #pragma unroll
        for (int it = 0; it < 4; ++it) {
            const int idx = tid + it * 256;
            const int r = idx >> 4, c4 = (idx & 15) * 4;
            float4 f = *reinterpret_cast<const float4*>(&W[(size_t)(r0 + r) * 512 + c0 + c4]);
            ts[r][c4 + 0] = f2bf(f.x); ts[r][c4 + 1] = f2bf(f.y);
            ts[r][c4 + 2] = f2bf(f.z); ts[r][c4 + 3] = f2bf(f.w);
        }
        __syncthreads();
        #pragma unroll
        for (int it = 0; it < 4; ++it) {
            const int idx = tid + it * 256;
            const int c = idx >> 4, r4 = (idx & 15) * 4;
            ushort4 o;
            o.x = ts[r4 + 0][c]; o.y = ts[r4 + 1][c];
            o.z = ts[r4 + 2][c]; o.w = ts[r4 + 3][c];
            *reinterpret_cast<ushort4*>(&WT[(size_t)(c0 + c) * 512 + r0 + r4]) = o;
        }
    } else {                                // W_out rows + folded biases
        const int v    = (bid - 256) * 4 + (tid >> 6);  // 0..511
        const int lane = tid & 63;
        float4 f0 = make_float4(0, 0, 0, 0), f1 = f0;
        if (v < V_) {
            f0 = *reinterpret_cast<const float4*>(&W_out[(size_t)v * 512 + lane * 8]);
            f1 = *reinterpret_cast<const float4*>(&W_out[(size_t)v * 512 + lane * 8 + 4]);
        }
        short8v o; o[0]=(short)f2bf(f0.x); o[1]=(short)f2bf(f0.y);
        o[2]=(short)f2bf(f0.z); o[3]=(short)f2bf(f0.w);
        o[4]=(short)f2bf(f1.x); o[5]=(short)f2bf(f1.y);
        o[6]=(short)f2bf(f1.z); o[7]=(short)f2bf(f1.w);
        *reinterpret_cast<short8v*>(WoB + (size_t)v * 512 + lane * 8) = o;

        float4 e0 = *reinterpret_cast<const float4*>(b_enc + lane * 8);
        float4 e1 = *reinterpret_cast<const float4*>(b_enc + lane * 8 + 4);
        float4 d0 = *reinterpret_cast<const float4*>(b_dec + lane * 8);
        float4 d1 = *reinterpret_cast<const float4*>(b_dec + lane * 8 + 4);
        float sE = f0.x*e0.x + f0.y*e0.y + f0.z*e0.z + f0.w*e0.w
                 + f1.x*e1.x + f1.y*e1.y + f1.z*e1.z + f1.w*e1.w;
        float sD = f0.x*d0.x + f0.y*d0.y + f0.z*d0.z + f0.w*d0.w
                 + f1.x*d1.x + f1.y*d1.y + f1.z*d1.z + f1.w*d1.w;
        #pragma unroll
        for (int off = 32; off > 0; off >>= 1) {
            sE += __shfl_down(sE, off);
            sD += __shfl_down(sD, off);
        }
        if (lane == 0) {
            be[v] = (v < V_) ? sE : 0.0f;
            bd[v] = (v < V_) ? (sD + b_out[v]) : 0.0f;
        }
    }
}

// ---------------------------------------------------------------------------
// bf16 NT GEMM body — round-3 exact (single-buffer BK=32, known-good).
// ---------------------------------------------------------------------------
template <bool OUT_BF16>
__device__ __forceinline__ void gemm_body(
    const ushort* __restrict__ A, const ushort* __restrict__ Bm,
    const float* __restrict__ bias, void* __restrict__ C,
    int m0, int n0)
{
    __shared__ ushort a_s[64 * 32];
    __shared__ ushort b_s[64 * 32];

    const int tid  = threadIdx.x;
    const int lane = tid & 63;
    const int wave = tid >> 6;
    const int wm   = wave >> 1, wn = wave & 1;

    ushort* a_dst = a_s + wave * 512;
    ushort* b_dst = b_s + wave * 512;
    const int srow = (wave << 4) + (lane >> 2);
    const int skc  = (lane & 3) * 8;

    const int r16 = lane & 15;
    const int kc  = lane >> 4;

    f32x4 acc[2][2] = {};

    for (int k0 = 0; k0 < KD; k0 += 32) {
        GLOAD16(A  + (size_t)(m0 + srow) * KD + k0 + skc, a_dst);
        GLOAD16(Bm + (size_t)(n0 + srow) * KD + k0 + skc, b_dst);
        __syncthreads();

        const short8v af0 = *reinterpret_cast<const short8v*>(&a_s[(wm*32 +      r16) * 32 + kc*8]);
        const short8v af1 = *reinterpret_cast<const short8v*>(&a_s[(wm*32 + 16 + r16) * 32 + kc*8]);
        const short8v bf0 = *reinterpret_cast<const short8v*>(&b_s[(wn*32 +      r16) * 32 + kc*8]);
        const short8v bf1 = *reinterpret_cast<const short8v*>(&b_s[(wn*32 + 16 + r16) * 32 + kc*8]);

        acc[0][0] = __builtin_amdgcn_mfma_f32_16x16x32_bf16(af0, bf0, acc[0][0], 0, 0, 0);
        acc[0][1] = __builtin_amdgcn_mfma_f32_16x16x32_bf16(af0, bf1, acc[0][1], 0, 0, 0);
        acc[1][0] = __builtin_amdgcn_mfma_f32_16x16x32_bf16(af1, bf0, acc[1][0], 0, 0, 0);
        acc[1][1] = __builtin_amdgcn_mfma_f32_16x16x32_bf16(af1, bf1, acc[1][1], 0, 0, 0);
        __syncthreads();
    }

    const int rb = (lane >> 4) * 4;
    #pragma unroll
    for (int m = 0; m < 2; ++m) {
        const int grow0 = m0 + wm * 32 + m * 16 + rb;
        #pragma unroll
        for (int n = 0; n < 2; ++n) {
            const int gcol = n0 + wn * 32 + n * 16 + r16;
            const float bv = bias ? bias[gcol] : 0.0f;
            #pragma unroll
            for (int r = 0; r < 4; ++r) {
                const float v = acc[m][n][r] + bv;
                if constexpr (OUT_BF16)
                    ((ushort*)C)[(size_t)(grow0 + r) * NP + gcol] = f2bf(v);
                else
                    ((float*)C)[(size_t)(grow0 + r) * NP + gcol] = v;
            }
        }
    }
}

// Wc_enc = WoB @ WeT^T (z=0), Wc_dec = WoB @ WdT^T (z=1); 512x512 bf16 out
__global__ __launch_bounds__(256) void wc_gemm(
    const ushort* __restrict__ WoB, const ushort* __restrict__ WeT,
    const ushort* __restrict__ WdT, ushort* __restrict__ WcE,
    ushort* __restrict__ WcD)
{
    const bool z = blockIdx.z != 0;
    gemm_body<true>(WoB, z ? WdT : WeT, nullptr, z ? WcD : WcE,
                    blockIdx.y * 64, blockIdx.x * 64);
}

// DV = decB @ WcD^T + bd   (512x512 f32; rows >= 480 garbage-but-unread)
__global__ __launch_bounds__(256) void dv_gemm(
    const ushort* __restrict__ decB, const ushort* __restrict__ WcD,
    const float* __restrict__ bd, float* __restrict__ DV)
{
    gemm_body<false>(decB, WcD, bd, DV, blockIdx.y * 64, blockIdx.x * 64);
}

// ---------------------------------------------------------------------------
// Fused EV GEMM + broadcast-add + contiguous output stream (PLAIN stores).
// Block = 12 bt-rows x FULL V; grid = 16 b x 25 tiles = 400 blocks, 512 thr.
//  - A (12x512 f32 -> bf16) staged once in LDS [16][520] (rows 12..15 zero)
//  - 8 waves x 64-col strips; 4 indep B-loads + 4 MFMA per k-step per wave
//  - B-fragments direct from L2-resident WcE (512 KB)
//  - EV via LDS [16][516] f32 (UNION with A tile; barrier-separated)
//  - DV slice in <=8 regs/thread; plain f32x4 stores, 1KB bursts per wave
// LDS = 33 KB union.
// ---------------------------------------------------------------------------
constexpr int RT = 12;                // bt-rows per tile (300 = 12*25)

__global__ __launch_bounds__(512) void fused_ev_stream(
    const float* __restrict__ enc, const ushort* __restrict__ WcE,
    const float* __restrict__ be, const float* __restrict__ DV,
    float* __restrict__ out)
{
    __shared__ __align__(16) char lsbuf[16 * 516 * 4];   // 33 KB union
    ushort* a_s = reinterpret_cast<ushort*>(lsbuf);      // [16][520] bf16
    float*  evs = reinterpret_cast<float*>(lsbuf);       // [16][516] f32

    const int tid  = threadIdx.x;
    const int lane = tid & 63;
    const int wave = tid >> 6;        // 0..7 -> 64-col strip
    const int b    = blockIdx.x / 25;
    const int tile = blockIdx.x - b * 25;
    const int bt0  = b * T_ + tile * RT;

    // ---- stage A: 16 rows x 512 cols, f32 -> bf16, rows >= RT zeroed ----
    #pragma unroll
    for (int it = 0; it < 4; ++it) {
        const int flat = it * 2048 + tid * 4;      // f32 index in 16x512
        const int r = flat >> 9;
        const int c = flat & 511;
        float4 f = make_float4(0.f, 0.f, 0.f, 0.f);
        if (r < RT)
            f = *reinterpret_cast<const float4*>(enc + (size_t)(bt0 + r) * KD + c);
        ushort4 o;
        o.x = f2bf(f.x); o.y = f2bf(f.y); o.z = f2bf(f.z); o.w = f2bf(f.w);
        *reinterpret_cast<ushort4*>(&a_s[r * 520 + c]) = o;
    }
    __syncthreads();

    // ---- GEMM: 16 rows x 64 cols per wave, K=512, B from L2 ----
    const int r16 = lane & 15;
    const int kc8 = (lane >> 4) * 8;
    const int cb  = wave * 64;
    f32x4 acc[4] = {};

    #pragma unroll 4
    for (int k0 = 0; k0 < KD; k0 += 32) {
        const short8v a0 = *reinterpret_cast<const short8v*>(&a_s[r16 * 520 + k0 + kc8]);
        #pragma unroll
        for (int n = 0; n < 4; ++n) {
            const short8v bf = *reinterpret_cast<const short8v*>(
                WcE + (size_t)(cb + n * 16 + r16) * KD + k0 + kc8);
            acc[n] = __builtin_amdgcn_mfma_f32_16x16x32_bf16(a0, bf, acc[n], 0, 0, 0);
        }
    }
    __syncthreads();   // all waves done reading a_s; LDS becomes evs

    // ---- evs = acc + be ----
    const int rb = (lane >> 4) * 4;
    #pragma unroll
    for (int n = 0; n < 4; ++n) {
        const int col = cb + n * 16 + r16;
        if (col < V_) {
            const float bv = be[col];
            #pragma unroll
            for (int r = 0; r < 4; ++r)
                evs[(rb + r) * 516 + col] = acc[n][r] + bv;
        }
    }
    __syncthreads();

    // ---- DV slice -> regs (u = ug + 4j), then contiguous plain stream ----
    const int v4 = tid & 127;         // 0..127, <125 active
    const int ug = tid >> 7;          // 0..3
    if (v4 < 125) {
        f32x4 dreg[8] = {};
        #pragma unroll
        for (int j = 0; j < 8; ++j) {
            const int u = ug + 4 * j;
            if (u < U_)
                dreg[j] = *reinterpret_cast<const f32x4*>(
                    DV + ((size_t)b * U_ + u) * NP + v4 * 4);
        }
        #pragma unroll
        for (int r = 0; r < RT; ++r) {
            const f32x4 e = *reinterpret_cast<const f32x4*>(&evs[r * 516 + v4 * 4]);
            float* base = out + ((size_t)(bt0 + r) * U_) * V_ + v4 * 4;
            #pragma unroll
            for (int j = 0; j < 8; ++j) {
                const int u = ug + 4 * j;
                if (u < U_)
                    *reinterpret_cast<f32x4*>(base + (size_t)u * V_) = e + dreg[j];
            }
        }
    }
}

extern "C" void kernel_launch(void* const* d_in, const int* in_sizes, int n_in,
                              void* d_out, int out_size, void* d_ws, size_t ws_size,
                              hipStream_t stream) {
    const float* enc   = (const float*)d_in[0];
    const float* dec   = (const float*)d_in[1];
    const float* W_enc = (const float*)d_in[2];
    const float* b_enc = (const float*)d_in[3];
    const float* W_dec = (const float*)d_in[4];
    const float* b_dec = (const float*)d_in[5];
    const float* W_out = (const float*)d_in[6];
    const float* b_out = (const float*)d_in[7];
    float* out = (float*)d_out;

    // Workspace (~4.2 MB)
    char* p = (char*)d_ws;
    ushort* decB = (ushort*)p;            p += (size_t)512 * 512 * 2;
    ushort* WeT  = (ushort*)p;            p += (size_t)512 * 512 * 2;
    ushort* WdT  = (ushort*)p;            p += (size_t)512 * 512 * 2;
    ushort* WoB  = (ushort*)p;            p += (size_t)512 * 512 * 2;
    ushort* WcE  = (ushort*)p;            p += (size_t)512 * 512 * 2;
    ushort* WcD  = (ushort*)p;            p += (size_t)512 * 512 * 2;
    float*  be   = (float*)p;             p += 512 * 4;
    float*  bd   = (float*)p;             p += 512 * 4;
    float*  DV   = (float*)p;                                  // 512x512 f32

    prep2<<<dim3(384), dim3(256), 0, stream>>>(
        dec, W_enc, W_dec, W_out, b_enc, b_dec, b_out,
        decB, WeT, WdT, WoB, be, bd);

    wc_gemm<<<dim3(8, 8, 2), dim3(256), 0, stream>>>(WoB, WeT, WdT, WcE, WcD);

    dv_gemm<<<dim3(8, 8), dim3(256), 0, stream>>>(decB, WcD, bd, DV);

    fused_ev_stream<<<dim3(400), dim3(512), 0, stream>>>(
        enc, WcE, be, DV, out);
}